// Round 12
// baseline (139.354 us; speedup 1.0000x reference)
//
#include <hip/hip_runtime.h>
#include <math.h>

// Gumbel subset (relaxed top-k) — B=2048 rows, N=8192, K=64 softmax steps.
// Multiplicative reformulation: v_i = exp(s0_i - M0), per step:
//   w = v*rinv(S); kh += w; v = fma(-w, v, v); part' = sum(v).
// R12: WAVE-PER-ROW. 64 lanes own a full row (128 elems/lane, 64 h2 packs
// each for v and kh). The per-iteration S-reduction is a pure wave-level
// shfl_xor chain: NO LDS roundtrip, NO __syncthreads, no inter-wave
// coupling (R6-R11: barrier+LDS machinery every 316 cy was the idle).
// Reduce overhead amortizes over 4x more elements per wave.
// Max via pass-1 stream + reload (inputs L2/L3-resident, ~4us equivalent).
// Inner math: R11's proven asm pk-f16 (2-pass, but fewest instructions):
//   nw = pk_mul(v, -rinv); kh = pk_fma(nw,-1,kh); v = pk_fma(nw,v,v).
// S-partials: fp16 accs at R11-proven depth (4 packs/acc) -> f32 tree.

typedef _Float16 h2 __attribute__((ext_vector_type(2)));

#define BROWS 2048
#define NCOLS 8192
#define KSTEPS 64

#define THREADS 256
#define WPB 4                    // waves (=rows) per block
#define EPL (NCOLS / 64)         // 128 elements per lane
#define NPK (EPL / 2)            // 64 h2 packs per lane
#define NACC 16                  // fp16 partial accumulators (4 packs each)

__global__ __launch_bounds__(THREADS, 2) void gumbel_subset_kernel(
    const float* __restrict__ scores,
    const float* __restrict__ g,
    float* __restrict__ out)
{
    const int wave = threadIdx.x >> 6;
    const int lane = threadIdx.x & 63;
    const int row = blockIdx.x * WPB + wave;
    const float* __restrict__ srow = scores + (size_t)row * NCOLS;
    const float* __restrict__ grow = g + (size_t)row * NCOLS;
    float* __restrict__ orow = out + (size_t)row * NCOLS;

    // ---- pass 1: stream s0 = scores + g, lane-local max only ----
    float m = -INFINITY;
#pragma unroll
    for (int c = 0; c < EPL / 4; ++c) {
        const int idx = c * 256 + lane * 4;
        const float4 a = *reinterpret_cast<const float4*>(srow + idx);
        const float4 b = *reinterpret_cast<const float4*>(grow + idx);
        m = fmaxf(m, fmaxf(fmaxf(a.x + b.x, a.y + b.y),
                           fmaxf(a.z + b.z, a.w + b.w)));
    }
    // wave max (exact, all lanes)
#pragma unroll
    for (int off = 32; off > 0; off >>= 1)
        m = fmaxf(m, __shfl_xor(m, off, 64));

    // ---- pass 2: reload (L2/L3-hot), v = exp(s0-m) fp16, kh = 0 ----
    h2 v[NPK];
    h2 kh[NPK];
    float part = 0.0f;
#pragma unroll
    for (int c = 0; c < EPL / 4; ++c) {
        const int idx = c * 256 + lane * 4;
        const float4 a = *reinterpret_cast<const float4*>(srow + idx);
        const float4 b = *reinterpret_cast<const float4*>(grow + idx);
        const float e0 = __expf(a.x + b.x - m);
        const float e1 = __expf(a.y + b.y - m);
        const float e2 = __expf(a.z + b.z - m);
        const float e3 = __expf(a.w + b.w - m);
        v[2 * c + 0] = (h2){(_Float16)e0, (_Float16)e1};
        v[2 * c + 1] = (h2){(_Float16)e2, (_Float16)e3};
        kh[2 * c + 0] = (h2){(_Float16)0.0f, (_Float16)0.0f};
        kh[2 * c + 1] = (h2){(_Float16)0.0f, (_Float16)0.0f};
        part += (e0 + e1) + (e2 + e3);
    }

    // ---- K relaxation steps (no barriers, pure wave) ----
    for (int it = 0; it < KSTEPS; ++it) {
        float s = part;
#pragma unroll
        for (int off = 32; off > 0; off >>= 1)
            s += __shfl_xor(s, off, 64);

        const float rinv = __builtin_amdgcn_rcpf(s);
        const h2 rn2 = (h2){(_Float16)(-rinv), (_Float16)(-rinv)};
        const h2 n1 = (h2){(_Float16)(-1.0f), (_Float16)(-1.0f)};

        float partf = 0.0f;
#pragma unroll
        for (int grp = 0; grp < NACC; ++grp) {
            h2 acc = (h2){(_Float16)0.0f, (_Float16)0.0f};
#pragma unroll
            for (int j = 0; j < 4; ++j) {
                const int p = grp * 4 + j;
                h2 nw, kn, vn, an;
                asm("v_pk_mul_f16 %0, %1, %2" : "=&v"(nw) : "v"(v[p]), "v"(rn2));
                asm("v_pk_fma_f16 %0, %1, %2, %3" : "=&v"(kn) : "v"(nw), "v"(n1), "v"(kh[p]));
                kh[p] = kn;
                asm("v_pk_fma_f16 %0, %1, %2, %3" : "=&v"(vn) : "v"(nw), "v"(v[p]), "v"(v[p]));
                v[p] = vn;
                asm("v_pk_add_f16 %0, %1, %2" : "=&v"(an) : "v"(acc), "v"(v[p]));
                acc = an;
            }
            partf += (float)acc.x + (float)acc.y;  // f32 tree at R11-proven acc depth
        }
        part = partf;
    }

    // ---- store khot (coalesced float4) ----
#pragma unroll
    for (int c = 0; c < EPL / 4; ++c) {
        const int idx = c * 256 + lane * 4;
        float4 o;
        o.x = (float)kh[2 * c + 0].x;
        o.y = (float)kh[2 * c + 0].y;
        o.z = (float)kh[2 * c + 1].x;
        o.w = (float)kh[2 * c + 1].y;
        *reinterpret_cast<float4*>(orow + idx) = o;
    }
}

extern "C" void kernel_launch(void* const* d_in, const int* in_sizes, int n_in,
                              void* d_out, int out_size, void* d_ws, size_t ws_size,
                              hipStream_t stream) {
    const float* scores = (const float*)d_in[0];
    const float* g = (const float*)d_in[1];
    float* out = (float*)d_out;
    (void)in_sizes; (void)n_in; (void)out_size; (void)d_ws; (void)ws_size;

    gumbel_subset_kernel<<<BROWS / WPB, THREADS, 0, stream>>>(scores, g, out);
}